// Round 5
// baseline (1352.517 us; speedup 1.0000x reference)
//
#include <hip/hip_runtime.h>
#include <hip/hip_bf16.h>

// Problem shape (fixed by reference setup_inputs)
constexpr int MM = 4096;   // tokens
constexpr int NN = 8192;   // outfeatures
constexpr int KK = 8192;   // infeatures
// Main kernel tile: 128x256, 8 waves (2M x 4N), wave tile 64x64
constexpr int AM = 128, AN = 256, BK = 64;
constexpr int THREADS = 512;
constexpr int NKB = KK / BK;    // 128
constexpr int NTN = NN / AN;    // 32 n-tiles
constexpr int NTM = MM / AM;    // 32 m-tiles

typedef _Float16 f16;
typedef __attribute__((ext_vector_type(2))) _Float16 f16x2;
typedef __attribute__((ext_vector_type(8))) _Float16 f16x8;
typedef __attribute__((ext_vector_type(4))) float floatx4;
typedef __attribute__((ext_vector_type(4))) int intx4;
typedef __bf16 bf16;
typedef __attribute__((ext_vector_type(8))) __bf16 bf16x8;

__device__ __forceinline__ void async_copy16(const void* g, void* l) {
    __builtin_amdgcn_global_load_lds(
        (const __attribute__((address_space(1))) void*)g,
        (__attribute__((address_space(3))) void*)l, 16, 0, 0);
}

// ---------------------------------------------------------------------------
// Prep 1: x fp32 -> f16, tile-major [mtile(32)][kb(128)][m(128)][chunk^swz],
// pair order (k0,k4,k1,k5,k2,k6,k3,k7) baked in. 4 chunks/thread.
// ---------------------------------------------------------------------------
__global__ __launch_bounds__(256)
void convert_x(const float* __restrict__ x, f16* __restrict__ xb) {
    const int base = blockIdx.x * 256 + threadIdx.x;   // 1,048,576 threads
#pragma unroll
    for (int it = 0; it < 4; ++it) {
        const int tid = base + it * 1048576;           // one 16B chunk (8 elems)
        const int c = tid & 7;
        const int m = (tid >> 3) & 127;
        const int kb = (tid >> 10) & 127;
        const int mtile = tid >> 17;
        const int row = mtile * AM + m;
        const int col = kb * 64 + c * 8;
        const float4* src = (const float4*)(x + (size_t)row * KK + col);
        const float4 f0 = src[0];   // k0..k3
        const float4 f1 = src[1];   // k4..k7
        f16x8 v;                    // pair order (k0,k4,k1,k5,k2,k6,k3,k7)
        v[0] = (f16)f0.x; v[1] = (f16)f1.x;
        v[2] = (f16)f0.y; v[3] = (f16)f1.y;
        v[4] = (f16)f0.z; v[5] = (f16)f1.z;
        v[6] = (f16)f0.w; v[7] = (f16)f1.w;
        const int dst_chunk = (tid & ~7) | (c ^ (m & 7));
        *(f16x8*)(xb + (size_t)dst_chunk * 8) = v;
    }
}

// ---------------------------------------------------------------------------
// Prep 2: packed-f16 group constants, per-lane contiguous:
//   spack[ntile(32)][g(64)][wq(4)][lane(64)][8 dwords] = {s_pk[0..3], nzp[0..3]}
//   s_pk = f16(scale) duplicated; nzp = f16 bits of -(1024+z+1) duplicated.
// 16 MiB (duplicated across quads so GEMM loads are trivial dwordx4).
// ---------------------------------------------------------------------------
__global__ __launch_bounds__(256)
void prepack_s(const float* __restrict__ scales, const unsigned* __restrict__ qzeros,
               unsigned* __restrict__ spack) {
    const int T = blockIdx.x * 256 + threadIdx.x;   // 524,288 threads
    const int lane = T & 63;
    const int wq   = (T >> 6) & 3;
    const int g    = (T >> 8) & 63;
    const int ntile = T >> 14;
    const int ml = lane & 15;
    unsigned sp[4], nz[4];
#pragma unroll
    for (int jn = 0; jn < 4; ++jn) {
        const int col = ntile * 256 + wq * 64 + ml + jn * 16;
        const float s = scales[(size_t)g * NN + col];
        const unsigned zw = qzeros[(size_t)g * (NN / 8) + (col >> 3)];
        const unsigned z = (zw >> (4 * (col & 7))) & 15u;
        const unsigned short sh = __builtin_bit_cast(unsigned short, (f16)s);
        sp[jn] = ((unsigned)sh << 16) | sh;
        const unsigned nh = 0xE401u + z;            // -(1024 + z + 1), exact
        nz[jn] = (nh << 16) | nh;
    }
    unsigned* dst = spack + (size_t)T * 8;
    *(intx4*)(dst + 0) = (intx4){(int)sp[0], (int)sp[1], (int)sp[2], (int)sp[3]};
    *(intx4*)(dst + 4) = (intx4){(int)nz[0], (int)nz[1], (int)nz[2], (int)nz[3]};
}

// ---------------------------------------------------------------------------
// Main GEMM. 128x256 tile, 8 waves (2M x 4N), wave tile 64x64, acc = 64 AGPR,
// launch_bounds(512,4) => <=128 regs/wave => 2 blocks/CU (16 waves).
//  - A: f16 tiles via global_load_lds, double-buffered 2x16KB, 1 barrier/kb.
//  - B: RAW qweight loads (no prepack): the address splits into a
//    wave-uniform row part (kb*8+ks*4)*NN -> SGPR base (SALU update) and a
//    kb-invariant per-lane part quad*NN + n0 + wq*64 + ml (+ j*16 via the
//    13-bit immediate) -> ONE voffset VGPR, zero per-kb VALU. Each 64B line
//    is fully covered by 16 lanes, so coalescing matches the packed layout.
//    Dequant in regs (packed-f16 magic, exact add-then-mul). M-wave dup: 2.
//  - Group constants: 2x dwordx4 from spack at end of odd kb.
//  - Bijective XCD-chunk swizzle for L2 locality on xb.
// ---------------------------------------------------------------------------
__global__ __launch_bounds__(THREADS, 4)
void qgemm(const f16* __restrict__ xb,
           const unsigned* __restrict__ qweight,
           const unsigned* __restrict__ spack,
           const float* __restrict__ bias,
           float* __restrict__ out)
{
    __shared__ alignas(16) f16 As[2][AM * BK];   // 2 x 16 KB

    const int t = threadIdx.x;
    // XCD-chunk swizzle (1024 % 8 == 0 -> bijective)
    const int v = (blockIdx.x & 7) * 128 + (blockIdx.x >> 3);
    const int ntile = v & (NTN - 1);
    const int mtile = v >> 5;
    const int n0 = ntile * AN;

    const int wave = t >> 6;
    const int lane = t & 63;
    const int wm = (wave >> 2) * 64;    // 2 waves along M
    const int wn = (wave & 3) * 64;     // 4 waves along N
    const int ml = lane & 15;
    const int quad = lane >> 4;
    const int wq = wave & 3;

    floatx4 acc[4][4];
#pragma unroll
    for (int i = 0; i < 4; ++i)
#pragma unroll
        for (int j = 0; j < 4; ++j)
            acc[i][j] = (floatx4){0.f, 0.f, 0.f, 0.f};

    // ---- state registers ----
    unsigned bq[8];             // raw qweight dwords for current kb [ks*4+j]
    unsigned s_pk[4], nzp[4];   // current group constants

    const char* xb_base = (const char*)xb
        + (size_t)mtile * NKB * (AM * BK) * sizeof(f16);
    // kb-invariant per-lane voffset into qweight (dword index)
    const unsigned voff = (unsigned)quad * NN + (unsigned)(n0 + wq * 64 + ml);
    // per-lane base into spack (dword index)
    const unsigned sp_base0 = (unsigned)ntile * 131072u + (unsigned)wq * 512u + lane * 8u;

    auto stage_a = [&](int kb, int buf) {
        const char* g = xb_base + (size_t)kb * (AM * BK * 2)
                      + wave * 2048 + lane * 16;
        char* l = (char*)&As[buf][0] + wave * 2048;   // wave-uniform; HW adds lane*16
#pragma unroll
        for (int i = 0; i < 2; ++i)
            async_copy16(g + i * 1024, l + i * 1024);
    };

    auto load_af = [&](int buf, int ks, f16x8 (&af)[4]) {
#pragma unroll
        for (int im = 0; im < 4; ++im) {
            const int r = wm + im * 16 + ml;
            const int clog = ks * 4 + quad;
            af[im] = *(const f16x8*)&As[buf][r * BK + ((clog ^ (r & 7)) << 3)];
        }
    };

    // 4 raw qweight dwords; row offset is wave-uniform (SGPR), j*16 folds
    // into the load immediate -> zero per-kb address VALU.
    auto load_bq = [&](int kb, int ks) {
        const unsigned ro = (unsigned)((kb * 8 + ks * 4) * NN);
#pragma unroll
        for (int j = 0; j < 4; ++j)
            bq[ks * 4 + j] = qweight[ro + voff + (unsigned)(j * 16)];
    };

    auto load_grp = [&](int g) {
        const unsigned idx = sp_base0 + (unsigned)g * 2048u;
        *(intx4*)&s_pk[0] = *(const intx4*)(spack + idx);
        *(intx4*)&nzp[0]  = *(const intx4*)(spack + idx + 4);
    };

    // dequant 4 B-fragments in registers + 16 MFMA
    auto phase = [&](int ks, const f16x8 (&af)[4]) {
        __builtin_amdgcn_s_setprio(1);
#pragma unroll
        for (int j = 0; j < 4; ++j) {
            const unsigned u = bq[ks * 4 + j];
            const unsigned t0 = ( u         & 0x000F000Fu) | 0x64006400u;  // (n0,n4)
            const unsigned t1 = ((u >> 4)   & 0x000F000Fu) | 0x64006400u;  // (n1,n5)
            const unsigned t2 = ((u >> 8)   & 0x000F000Fu) | 0x64006400u;  // (n2,n6)
            const unsigned t3 = ((u >> 12)  & 0x000F000Fu) | 0x64006400u;  // (n3,n7)
            const f16x2 z2 = __builtin_bit_cast(f16x2, nzp[j]);
            const f16x2 sp = __builtin_bit_cast(f16x2, s_pk[j]);
            const f16x2 w0 = (__builtin_bit_cast(f16x2, t0) + z2) * sp;
            const f16x2 w1 = (__builtin_bit_cast(f16x2, t1) + z2) * sp;
            const f16x2 w2 = (__builtin_bit_cast(f16x2, t2) + z2) * sp;
            const f16x2 w3 = (__builtin_bit_cast(f16x2, t3) + z2) * sp;
            const intx4 bi = { __builtin_bit_cast(int, w0), __builtin_bit_cast(int, w1),
                               __builtin_bit_cast(int, w2), __builtin_bit_cast(int, w3) };
            const f16x8 bfr = __builtin_bit_cast(f16x8, bi);
#pragma unroll
            for (int im = 0; im < 4; ++im)
                acc[im][j] = __builtin_amdgcn_mfma_f32_16x16x32_f16(
                    af[im], bfr, acc[im][j], 0, 0, 0);
        }
        __builtin_amdgcn_s_setprio(0);
    };

    // One K-block. `odd` is a compile-time literal at every call site.
    auto body = [&](int kb, int buf, bool stage, bool odd) {
        f16x8 af[4];
        if (stage) stage_a(kb + 1, buf ^ 1);   // DMA earliest: longest window
        load_af(buf, 0, af);
        phase(0, af);
        if (stage) load_bq(kb + 1, 0);         // reload consumed half (WAR)
        load_af(buf, 1, af);
        phase(1, af);
        if (stage) load_bq(kb + 1, 1);
        if (stage && odd) load_grp((kb + 1) >> 1);  // after last use of group
        if (stage) __syncthreads();            // drains DMA + bq + grp loads
    };

    // ---- prologue ----
    load_grp(0);
    stage_a(0, 0);
    load_bq(0, 0); load_bq(0, 1);
    __syncthreads();

    // ---- main loop, unrolled x2 for static buffer indices ----
    for (int kb = 0; kb < NKB - 2; kb += 2) {
        body(kb, 0, true, false);
        body(kb + 1, 1, true, true);
    }
    body(NKB - 2, 0, true, false);
    body(NKB - 1, 1, false, true);

    // ---- epilogue: C/D layout col=lane&15, row=quad*4+reg; add bias ----
#pragma unroll
    for (int jn = 0; jn < 4; ++jn) {
        const int ngl = n0 + wn + jn * 16 + ml;
        const float bv = bias[ngl];
#pragma unroll
        for (int im = 0; im < 4; ++im) {
            const int mg = mtile * AM + wm + im * 16 + quad * 4;
#pragma unroll
            for (int r = 0; r < 4; ++r)
                out[(size_t)(mg + r) * NN + ngl] = acc[im][jn][r] + bv;
        }
    }
}

// ---------------------------------------------------------------------------
// Fallback (round-0 structure, known-good, 256x256): only if ws too small.
// ---------------------------------------------------------------------------
__global__ __launch_bounds__(512, 2)
void qgemm_fallback(const float* __restrict__ x,
                    const unsigned* __restrict__ qweight,
                    const unsigned* __restrict__ qzeros,
                    const float* __restrict__ scales,
                    const float* __restrict__ bias,
                    float* __restrict__ out)
{
    constexpr int FBM = 256, FBN = 256;
    __shared__ bf16 As[FBM * BK];
    __shared__ bf16 Bs[FBN * BK];

    const int t = threadIdx.x;
    const int ntile = blockIdx.x & 31;
    const int mtile = blockIdx.x >> 5;
    const int m0 = mtile * FBM;
    const int n0 = ntile * FBN;
    const int wave = t >> 6;
    const int lane = t & 63;
    const int wm = (wave >> 1) * 64;
    const int wn = (wave & 1) * 128;
    const int ml = lane & 15;
    const int quad = lane >> 4;
    const int bn = t & 255;
    const int rbase = (t >> 8) * 4;
    const int gn = n0 + bn;

    floatx4 acc[4][8];
    for (int i = 0; i < 4; ++i)
        for (int j = 0; j < 8; ++j)
            acc[i][j] = (floatx4){0.f, 0.f, 0.f, 0.f};

    float s = 0.f, sz = 0.f;

    for (int kb = 0; kb < KK / BK; ++kb) {
        const int k0 = kb * BK;
        if ((kb & 1) == 0) {
            const int g = kb >> 1;
            s = scales[g * NN + gn];
            const unsigned zw = qzeros[g * (NN / 8) + (gn >> 3)];
            const float z = (float)(((zw >> (4 * (gn & 7))) & 15u) + 1u);
            sz = s * z;
        }
#pragma unroll
        for (int i = 0; i < 4; ++i) {
            const int chunk = t + 512 * i;
            const int m = chunk >> 3;
            const int c = chunk & 7;
            const float4* src = (const float4*)(x + (size_t)(m0 + m) * KK + (k0 + c * 8));
            const float4 f0 = src[0];
            const float4 f1 = src[1];
            bf16x8 v;
            v[0] = (bf16)f0.x; v[1] = (bf16)f0.y; v[2] = (bf16)f0.z; v[3] = (bf16)f0.w;
            v[4] = (bf16)f1.x; v[5] = (bf16)f1.y; v[6] = (bf16)f1.z; v[7] = (bf16)f1.w;
            *(bf16x8*)&As[m * BK + ((c ^ (m & 7)) << 3)] = v;
        }
        const int kq0 = k0 >> 3;
#pragma unroll
        for (int i = 0; i < 4; ++i) {
            const int rq = rbase + i;
            const unsigned q = qweight[(size_t)(kq0 + rq) * NN + gn];
            bf16x8 v;
#pragma unroll
            for (int j = 0; j < 8; ++j) {
                const float f = (float)((q >> (4 * j)) & 15u) * s - sz;
                v[j] = (bf16)f;
            }
            *(bf16x8*)&Bs[bn * BK + ((rq ^ (bn & 7)) << 3)] = v;
        }
        __syncthreads();
#pragma unroll
        for (int ks = 0; ks < 2; ++ks) {
            const int clog = ks * 4 + quad;
            bf16x8 af[4];
            bf16x8 bfr[8];
#pragma unroll
            for (int im = 0; im < 4; ++im) {
                const int row = wm + im * 16 + ml;
                af[im] = *(const bf16x8*)&As[row * BK + ((clog ^ (row & 7)) << 3)];
            }
#pragma unroll
            for (int jn = 0; jn < 8; ++jn) {
                const int row = wn + jn * 16 + ml;
                bfr[jn] = *(const bf16x8*)&Bs[row * BK + ((clog ^ (row & 7)) << 3)];
            }
#pragma unroll
            for (int im = 0; im < 4; ++im)
#pragma unroll
                for (int jn = 0; jn < 8; ++jn)
                    acc[im][jn] = __builtin_amdgcn_mfma_f32_16x16x32_bf16(
                        af[im], bfr[jn], acc[im][jn], 0, 0, 0);
        }
        __syncthreads();
    }
#pragma unroll
    for (int jn = 0; jn < 8; ++jn) {
        const int ngl = n0 + wn + jn * 16 + ml;
        const float bv = bias[ngl];
#pragma unroll
        for (int im = 0; im < 4; ++im) {
            const int mg = m0 + wm + im * 16 + quad * 4;
#pragma unroll
            for (int r = 0; r < 4; ++r)
                out[(size_t)(mg + r) * NN + ngl] = acc[im][jn][r] + bv;
        }
    }
}

extern "C" void kernel_launch(void* const* d_in, const int* in_sizes, int n_in,
                              void* d_out, int out_size, void* d_ws, size_t ws_size,
                              hipStream_t stream) {
    const float*    x       = (const float*)d_in[0];
    const unsigned* qweight = (const unsigned*)d_in[1];
    const unsigned* qzeros  = (const unsigned*)d_in[2];
    const float*    scales  = (const float*)d_in[3];
    const float*    bias    = (const float*)d_in[4];
    float* out = (float*)d_out;

    const size_t xb_bytes = (size_t)MM * KK * sizeof(f16);        // 64 MiB
    const size_t sp_bytes = (size_t)32 * 64 * 4 * 64 * 8 * 4;     // 16 MiB

    if (ws_size >= xb_bytes + sp_bytes) {
        f16*      xb    = (f16*)d_ws;
        unsigned* spack = (unsigned*)((char*)d_ws + xb_bytes);
        convert_x<<<4096, 256, 0, stream>>>(x, xb);
        prepack_s<<<2048, 256, 0, stream>>>(scales, qzeros, spack);
        const int grid = NTM * NTN;   // 1024 blocks
        qgemm<<<grid, THREADS, 0, stream>>>(xb, qweight, spack, bias, out);
    } else {
        const int grid = (MM / 256) * (NN / 256);   // 512 blocks
        qgemm_fallback<<<grid, 512, 0, stream>>>(x, qweight, qzeros, scales, bias, out);
    }
}

// Round 6
// 792.455 us; speedup vs baseline: 1.7067x; 1.7067x over previous
//
#include <hip/hip_runtime.h>
#include <hip/hip_bf16.h>

// Problem shape (fixed by reference setup_inputs)
constexpr int MM = 4096;   // tokens
constexpr int NN = 8192;   // outfeatures
constexpr int KK = 8192;   // infeatures
// Main kernel tile: 128x256, 8 waves (2M x 4N), wave tile 64x64
constexpr int AM = 128, AN = 256, BK = 64;
constexpr int THREADS = 512;
constexpr int NKB = KK / BK;    // 128
constexpr int NTN = NN / AN;    // 32 n-tiles
constexpr int NTM = MM / AM;    // 32 m-tiles

typedef _Float16 f16;
typedef __attribute__((ext_vector_type(2))) _Float16 f16x2;
typedef __attribute__((ext_vector_type(8))) _Float16 f16x8;
typedef __attribute__((ext_vector_type(4))) float floatx4;
typedef __attribute__((ext_vector_type(4))) int intx4;
typedef __bf16 bf16;
typedef __attribute__((ext_vector_type(8))) __bf16 bf16x8;

__device__ __forceinline__ void async_copy16(const void* g, void* l) {
    __builtin_amdgcn_global_load_lds(
        (const __attribute__((address_space(1))) void*)g,
        (__attribute__((address_space(3))) void*)l, 16, 0, 0);
}

// ---------------------------------------------------------------------------
// Fused prep (ONE dispatch, roles by block range — removes 2 launch gaps and
// overlaps the small prepacks with convert's tail):
//  blocks [0,4096):      x fp32 -> f16 tile-major
//                        [mtile(32)][kb(128)][m(128)][chunk^swz], pair order
//                        (k0,k4,k1,k5,k2,k6,k3,k7) baked in.
//  blocks [4096,12288):  qweight -> bpack[ntile][kb][wq][lane][ks][j]
//                        (per-lane-contiguous dwordx4 consumption order).
//  blocks [12288,14336): packed-f16 group constants spack[ntile][g][wq][lane]
//                        {s_pk[0..3], nzp[0..3]}; nzp = -(1024+z+1) exact.
// ---------------------------------------------------------------------------
__global__ __launch_bounds__(256)
void prep_all(const float* __restrict__ x,
              const unsigned* __restrict__ qweight,
              const float* __restrict__ scales,
              const unsigned* __restrict__ qzeros,
              f16* __restrict__ xb,
              unsigned* __restrict__ bpack,
              unsigned* __restrict__ spack)
{
    const int b = blockIdx.x;
    if (b < 4096) {
        // ---- convert_x role ----
        const int base = b * 256 + threadIdx.x;
#pragma unroll
        for (int it = 0; it < 4; ++it) {
            const int tid = base + it * 1048576;       // one 16B chunk (8 elems)
            const int c = tid & 7;
            const int m = (tid >> 3) & 127;
            const int kb = (tid >> 10) & 127;
            const int mtile = tid >> 17;
            const int row = mtile * AM + m;
            const int col = kb * 64 + c * 8;
            const float4* src = (const float4*)(x + (size_t)row * KK + col);
            const float4 f0 = src[0];   // k0..k3
            const float4 f1 = src[1];   // k4..k7
            f16x8 v;                    // pair order (k0,k4,k1,k5,k2,k6,k3,k7)
            v[0] = (f16)f0.x; v[1] = (f16)f1.x;
            v[2] = (f16)f0.y; v[3] = (f16)f1.y;
            v[4] = (f16)f0.z; v[5] = (f16)f1.z;
            v[6] = (f16)f0.w; v[7] = (f16)f1.w;
            const int dst_chunk = (tid & ~7) | (c ^ (m & 7));
            *(f16x8*)(xb + (size_t)dst_chunk * 8) = v;
        }
    } else if (b < 4096 + 8192) {
        // ---- prepack_b role ----
        const int C = (b - 4096) * 256 + threadIdx.x;   // 2,097,152 chunks
        const int ks   = C & 1;
        const int lane = (C >> 1) & 63;
        const int wq   = (C >> 7) & 3;
        const int kb   = (C >> 9) & 127;
        const int ntile = C >> 16;
        const int quad = lane >> 4, ml = lane & 15;
        const int row = kb * 8 + ks * 4 + quad;
        const int colbase = ntile * 256 + wq * 64 + ml;
        intx4 v;
#pragma unroll
        for (int j = 0; j < 4; ++j)
            v[j] = (int)qweight[(size_t)row * NN + colbase + j * 16];
        *(intx4*)(bpack + (size_t)C * 4) = v;
    } else {
        // ---- prepack_s role ----
        const int T = (b - 12288) * 256 + threadIdx.x;  // 524,288 threads
        const int lane = T & 63;
        const int wq   = (T >> 6) & 3;
        const int g    = (T >> 8) & 63;
        const int ntile = T >> 14;
        const int ml = lane & 15;
        unsigned sp[4], nz[4];
#pragma unroll
        for (int jn = 0; jn < 4; ++jn) {
            const int col = ntile * 256 + wq * 64 + ml + jn * 16;
            const float s = scales[(size_t)g * NN + col];
            const unsigned zw = qzeros[(size_t)g * (NN / 8) + (col >> 3)];
            const unsigned z = (zw >> (4 * (col & 7))) & 15u;
            const unsigned short sh = __builtin_bit_cast(unsigned short, (f16)s);
            sp[jn] = ((unsigned)sh << 16) | sh;
            const unsigned nh = 0xE401u + z;            // -(1024 + z + 1), exact
            nz[jn] = (nh << 16) | nh;
        }
        unsigned* dst = spack + (size_t)T * 8;
        *(intx4*)(dst + 0) = (intx4){(int)sp[0], (int)sp[1], (int)sp[2], (int)sp[3]};
        *(intx4*)(dst + 4) = (intx4){(int)nz[0], (int)nz[1], (int)nz[2], (int)nz[3]};
    }
}

// ---------------------------------------------------------------------------
// Main GEMM — EXACT round-4 version (proven 554 us, no spills).
// 128x256 tile, 8 waves (2M x 4N), wave tile 64x64, acc = 64 AGPR,
// launch_bounds(512,4) => <=128 regs/wave => 2 blocks/CU (16 waves).
// NOTE: at this geometry the VGPR side is EXACTLY full (64) — do not add
// live values to the K-loop (round-5 lesson: +4 regs => 1.6 GB scratch).
//  - A: f16 tiles via global_load_lds, double-buffered 2x16KB, 1 barrier/kb.
//  - B: 2x dwordx4/lane/kb from bpack (single precomputed voffset), dequant
//    in regs (packed-f16 magic, exact add-then-mul). M-wave dup: 2.
//  - Group constants: 2x dwordx4 from spack at end of odd kb.
//  - Bijective XCD-chunk swizzle for L2 locality on xb.
// ---------------------------------------------------------------------------
__global__ __launch_bounds__(THREADS, 4)
void qgemm(const f16* __restrict__ xb,
           const unsigned* __restrict__ bpack,
           const unsigned* __restrict__ spack,
           const float* __restrict__ bias,
           float* __restrict__ out)
{
    __shared__ alignas(16) f16 As[2][AM * BK];   // 2 x 16 KB

    const int t = threadIdx.x;
    // XCD-chunk swizzle (1024 % 8 == 0 -> bijective)
    const int v = (blockIdx.x & 7) * 128 + (blockIdx.x >> 3);
    const int ntile = v & (NTN - 1);
    const int mtile = v >> 5;
    const int n0 = ntile * AN;

    const int wave = t >> 6;
    const int lane = t & 63;
    const int wm = (wave >> 2) * 64;    // 2 waves along M
    const int wn = (wave & 3) * 64;     // 4 waves along N
    const int ml = lane & 15;
    const int quad = lane >> 4;
    const int wq = wave & 3;

    floatx4 acc[4][4];
#pragma unroll
    for (int i = 0; i < 4; ++i)
#pragma unroll
        for (int j = 0; j < 4; ++j)
            acc[i][j] = (floatx4){0.f, 0.f, 0.f, 0.f};

    // ---- state registers ----
    unsigned bq[8];             // raw qweight dwords for current kb [ks*4+j]
    unsigned s_pk[4], nzp[4];   // current group constants

    const char* xb_base = (const char*)xb
        + (size_t)mtile * NKB * (AM * BK) * sizeof(f16);
    // per-lane bases (dword indices)
    const unsigned bq_base0 = (unsigned)ntile * 262144u + (unsigned)wq * 512u + lane * 8u;
    const unsigned sp_base0 = (unsigned)ntile * 131072u + (unsigned)wq * 512u + lane * 8u;

    auto stage_a = [&](int kb, int buf) {
        const char* g = xb_base + (size_t)kb * (AM * BK * 2)
                      + wave * 2048 + lane * 16;
        char* l = (char*)&As[buf][0] + wave * 2048;   // wave-uniform; HW adds lane*16
#pragma unroll
        for (int i = 0; i < 2; ++i)
            async_copy16(g + i * 1024, l + i * 1024);
    };

    auto load_af = [&](int buf, int ks, f16x8 (&af)[4]) {
#pragma unroll
        for (int im = 0; im < 4; ++im) {
            const int r = wm + im * 16 + ml;
            const int clog = ks * 4 + quad;
            af[im] = *(const f16x8*)&As[buf][r * BK + ((clog ^ (r & 7)) << 3)];
        }
    };

    auto load_bq = [&](int kb, int ks) {
        const unsigned idx = bq_base0 + (unsigned)kb * 2048u + (unsigned)ks * 4u;
        *(intx4*)&bq[ks * 4] = *(const intx4*)(bpack + idx);
    };

    auto load_grp = [&](int g) {
        const unsigned idx = sp_base0 + (unsigned)g * 2048u;
        *(intx4*)&s_pk[0] = *(const intx4*)(spack + idx);
        *(intx4*)&nzp[0]  = *(const intx4*)(spack + idx + 4);
    };

    // dequant 4 B-fragments in registers + 16 MFMA
    auto phase = [&](int ks, const f16x8 (&af)[4]) {
        __builtin_amdgcn_s_setprio(1);
#pragma unroll
        for (int j = 0; j < 4; ++j) {
            const unsigned u = bq[ks * 4 + j];
            const unsigned t0 = ( u         & 0x000F000Fu) | 0x64006400u;  // (n0,n4)
            const unsigned t1 = ((u >> 4)   & 0x000F000Fu) | 0x64006400u;  // (n1,n5)
            const unsigned t2 = ((u >> 8)   & 0x000F000Fu) | 0x64006400u;  // (n2,n6)
            const unsigned t3 = ((u >> 12)  & 0x000F000Fu) | 0x64006400u;  // (n3,n7)
            const f16x2 z2 = __builtin_bit_cast(f16x2, nzp[j]);
            const f16x2 sp = __builtin_bit_cast(f16x2, s_pk[j]);
            const f16x2 w0 = (__builtin_bit_cast(f16x2, t0) + z2) * sp;
            const f16x2 w1 = (__builtin_bit_cast(f16x2, t1) + z2) * sp;
            const f16x2 w2 = (__builtin_bit_cast(f16x2, t2) + z2) * sp;
            const f16x2 w3 = (__builtin_bit_cast(f16x2, t3) + z2) * sp;
            const intx4 bi = { __builtin_bit_cast(int, w0), __builtin_bit_cast(int, w1),
                               __builtin_bit_cast(int, w2), __builtin_bit_cast(int, w3) };
            const f16x8 bfr = __builtin_bit_cast(f16x8, bi);
#pragma unroll
            for (int im = 0; im < 4; ++im)
                acc[im][j] = __builtin_amdgcn_mfma_f32_16x16x32_f16(
                    af[im], bfr, acc[im][j], 0, 0, 0);
        }
        __builtin_amdgcn_s_setprio(0);
    };

    // One K-block. `odd` is a compile-time literal at every call site.
    auto body = [&](int kb, int buf, bool stage, bool odd) {
        f16x8 af[4];
        if (stage) stage_a(kb + 1, buf ^ 1);   // DMA earliest: longest window
        load_af(buf, 0, af);
        phase(0, af);
        if (stage) load_bq(kb + 1, 0);         // reload consumed half (WAR)
        load_af(buf, 1, af);
        phase(1, af);
        if (stage) load_bq(kb + 1, 1);
        if (stage && odd) load_grp((kb + 1) >> 1);  // after last use of group
        if (stage) __syncthreads();            // drains DMA + bq + grp loads
    };

    // ---- prologue ----
    load_grp(0);
    stage_a(0, 0);
    load_bq(0, 0); load_bq(0, 1);
    __syncthreads();

    // ---- main loop, unrolled x2 for static buffer indices ----
    for (int kb = 0; kb < NKB - 2; kb += 2) {
        body(kb, 0, true, false);
        body(kb + 1, 1, true, true);
    }
    body(NKB - 2, 0, true, false);
    body(NKB - 1, 1, false, true);

    // ---- epilogue: C/D layout col=lane&15, row=quad*4+reg; add bias ----
#pragma unroll
    for (int jn = 0; jn < 4; ++jn) {
        const int ngl = n0 + wn + jn * 16 + ml;
        const float bv = bias[ngl];
#pragma unroll
        for (int im = 0; im < 4; ++im) {
            const int mg = mtile * AM + wm + im * 16 + quad * 4;
#pragma unroll
            for (int r = 0; r < 4; ++r)
                out[(size_t)(mg + r) * NN + ngl] = acc[im][jn][r] + bv;
        }
    }
}

// ---------------------------------------------------------------------------
// Fallback (round-0 structure, known-good, 256x256): only if ws too small.
// ---------------------------------------------------------------------------
__global__ __launch_bounds__(512, 2)
void qgemm_fallback(const float* __restrict__ x,
                    const unsigned* __restrict__ qweight,
                    const unsigned* __restrict__ qzeros,
                    const float* __restrict__ scales,
                    const float* __restrict__ bias,
                    float* __restrict__ out)
{
    constexpr int FBM = 256, FBN = 256;
    __shared__ bf16 As[FBM * BK];
    __shared__ bf16 Bs[FBN * BK];

    const int t = threadIdx.x;
    const int ntile = blockIdx.x & 31;
    const int mtile = blockIdx.x >> 5;
    const int m0 = mtile * FBM;
    const int n0 = ntile * FBN;
    const int wave = t >> 6;
    const int lane = t & 63;
    const int wm = (wave >> 1) * 64;
    const int wn = (wave & 1) * 128;
    const int ml = lane & 15;
    const int quad = lane >> 4;
    const int bn = t & 255;
    const int rbase = (t >> 8) * 4;
    const int gn = n0 + bn;

    floatx4 acc[4][8];
    for (int i = 0; i < 4; ++i)
        for (int j = 0; j < 8; ++j)
            acc[i][j] = (floatx4){0.f, 0.f, 0.f, 0.f};

    float s = 0.f, sz = 0.f;

    for (int kb = 0; kb < KK / BK; ++kb) {
        const int k0 = kb * BK;
        if ((kb & 1) == 0) {
            const int g = kb >> 1;
            s = scales[g * NN + gn];
            const unsigned zw = qzeros[g * (NN / 8) + (gn >> 3)];
            const float z = (float)(((zw >> (4 * (gn & 7))) & 15u) + 1u);
            sz = s * z;
        }
#pragma unroll
        for (int i = 0; i < 4; ++i) {
            const int chunk = t + 512 * i;
            const int m = chunk >> 3;
            const int c = chunk & 7;
            const float4* src = (const float4*)(x + (size_t)(m0 + m) * KK + (k0 + c * 8));
            const float4 f0 = src[0];
            const float4 f1 = src[1];
            bf16x8 v;
            v[0] = (bf16)f0.x; v[1] = (bf16)f0.y; v[2] = (bf16)f0.z; v[3] = (bf16)f0.w;
            v[4] = (bf16)f1.x; v[5] = (bf16)f1.y; v[6] = (bf16)f1.z; v[7] = (bf16)f1.w;
            *(bf16x8*)&As[m * BK + ((c ^ (m & 7)) << 3)] = v;
        }
        const int kq0 = k0 >> 3;
#pragma unroll
        for (int i = 0; i < 4; ++i) {
            const int rq = rbase + i;
            const unsigned q = qweight[(size_t)(kq0 + rq) * NN + gn];
            bf16x8 v;
#pragma unroll
            for (int j = 0; j < 8; ++j) {
                const float f = (float)((q >> (4 * j)) & 15u) * s - sz;
                v[j] = (bf16)f;
            }
            *(bf16x8*)&Bs[bn * BK + ((rq ^ (bn & 7)) << 3)] = v;
        }
        __syncthreads();
#pragma unroll
        for (int ks = 0; ks < 2; ++ks) {
            const int clog = ks * 4 + quad;
            bf16x8 af[4];
            bf16x8 bfr[8];
#pragma unroll
            for (int im = 0; im < 4; ++im) {
                const int row = wm + im * 16 + ml;
                af[im] = *(const bf16x8*)&As[row * BK + ((clog ^ (row & 7)) << 3)];
            }
#pragma unroll
            for (int jn = 0; jn < 8; ++jn) {
                const int row = wn + jn * 16 + ml;
                bfr[jn] = *(const bf16x8*)&Bs[row * BK + ((clog ^ (row & 7)) << 3)];
            }
#pragma unroll
            for (int im = 0; im < 4; ++im)
#pragma unroll
                for (int jn = 0; jn < 8; ++jn)
                    acc[im][jn] = __builtin_amdgcn_mfma_f32_16x16x32_bf16(
                        af[im], bfr[jn], acc[im][jn], 0, 0, 0);
        }
        __syncthreads();
    }
#pragma unroll
    for (int jn = 0; jn < 8; ++jn) {
        const int ngl = n0 + wn + jn * 16 + ml;
        const float bv = bias[ngl];
#pragma unroll
        for (int im = 0; im < 4; ++im) {
            const int mg = m0 + wm + im * 16 + quad * 4;
#pragma unroll
            for (int r = 0; r < 4; ++r)
                out[(size_t)(mg + r) * NN + ngl] = acc[im][jn][r] + bv;
        }
    }
}

extern "C" void kernel_launch(void* const* d_in, const int* in_sizes, int n_in,
                              void* d_out, int out_size, void* d_ws, size_t ws_size,
                              hipStream_t stream) {
    const float*    x       = (const float*)d_in[0];
    const unsigned* qweight = (const unsigned*)d_in[1];
    const unsigned* qzeros  = (const unsigned*)d_in[2];
    const float*    scales  = (const float*)d_in[3];
    const float*    bias    = (const float*)d_in[4];
    float* out = (float*)d_out;

    const size_t xb_bytes = (size_t)MM * KK * sizeof(f16);        // 64 MiB
    const size_t bp_bytes = (size_t)(KK / 8) * NN * 4;            // 32 MiB
    const size_t sp_bytes = (size_t)32 * 64 * 4 * 64 * 8 * 4;     // 16 MiB

    if (ws_size >= xb_bytes + bp_bytes + sp_bytes) {
        f16*      xb    = (f16*)d_ws;
        unsigned* bpack = (unsigned*)((char*)d_ws + xb_bytes);
        unsigned* spack = (unsigned*)((char*)d_ws + xb_bytes + bp_bytes);
        prep_all<<<14336, 256, 0, stream>>>(x, qweight, scales, qzeros,
                                            xb, bpack, spack);
        const int grid = NTM * NTN;   // 1024 blocks
        qgemm<<<grid, THREADS, 0, stream>>>(xb, bpack, spack, bias, out);
    } else {
        const int grid = (MM / 256) * (NN / 256);   // 512 blocks
        qgemm_fallback<<<grid, 512, 0, stream>>>(x, qweight, qzeros, scales, bias, out);
    }
}